// Round 6
// baseline (243.472 us; speedup 1.0000x reference)
//
#include <hip/hip_runtime.h>

typedef __attribute__((ext_vector_type(8))) short short8;
typedef __attribute__((ext_vector_type(4))) float f32x4;
typedef __attribute__((ext_vector_type(4))) unsigned short u16x4;
typedef __attribute__((ext_vector_type(4))) unsigned int u32x4;

#define MFMA16(A,B,C) __builtin_amdgcn_mfma_f32_16x16x32_bf16(A,B,C,0,0,0)

__device__ __forceinline__ unsigned short f2bf(float f) {
  unsigned int u = __builtin_bit_cast(unsigned int, f);
  unsigned int r = (u + 0x7fffu + ((u >> 16) & 1u)) >> 16;
  return (unsigned short)r;
}

__device__ __forceinline__ unsigned int cvt_pk_bf16(float lo, float hi) {
  unsigned int r;
  asm("v_cvt_pk_bf16_f32 %0, %1, %2" : "=v"(r) : "v"(lo), "v"(hi));
  return r;
}

__device__ __forceinline__ f32x4 zero4() {
  f32x4 z; z.x = 0.f; z.y = 0.f; z.z = 0.f; z.w = 0.f; return z;
}

__device__ __forceinline__ void gl_lds16(const void* g, void* l) {
  __builtin_amdgcn_global_load_lds((const __attribute__((address_space(1))) void*)g,
                                   (__attribute__((address_space(3))) void*)l, 16, 0, 0);
}

// ---------------- convert all five f32 arrays to bf16 in one pass ----------------
// W_qk rows with (row & 127) < 64 (the q-projection rows) are pre-scaled by
// (1/sqrt(hd)) * log2(e) so attention can use exp2 directly on QK^T output.
__global__ __launch_bounds__(256) void cvt_all(const float* __restrict__ xe,
                                               const float* __restrict__ xd,
                                               const float* __restrict__ wqk,
                                               const float* __restrict__ wv,
                                               const float* __restrict__ wo,
                                               unsigned short* __restrict__ ws) {
  long i = (long)blockIdx.x * 256 + threadIdx.x;  // float4 index
  const float* src; unsigned short* dst; long o; bool scl = false;
  if (i < 1048576)      { src = xe;  dst = ws + 8650752;  o = i; }            // xe_bf
  else if (i < 2097152) { src = xd;  dst = ws + 12845056; o = i - 1048576; }  // xd_bf
  else if (i < 2621440) { src = wqk; dst = ws + 17039360; o = i - 2097152;    // wqk_bf
                          scl = (((o >> 8) & 127) < 64); }                    // q rows
  else if (i < 2883584) { src = wv;  dst = ws + 19136512; o = i - 2621440; }  // wv_bf
  else                  { src = wo;  dst = ws + 20185088; o = i - 2883584; }  // wo_bf
  float4 f = ((const float4*)src)[o];
  if (scl) {
    const float SCQ = 0.125f * 1.4426950408889634f;
    f.x *= SCQ; f.y *= SCQ; f.z *= SCQ; f.w *= SCQ;
  }
  u16x4 r; r.x = f2bf(f.x); r.y = f2bf(f.y); r.z = f2bf(f.z); r.w = f2bf(f.w);
  ((u16x4*)dst)[o] = r;
}

// ---------------- pack mask (2048x2048 int32) into bits ----------------
__global__ __launch_bounds__(256) void mask_pack(const int* __restrict__ mask,
                                                 unsigned int* __restrict__ mbits) {
  int idx = blockIdx.x * 256 + threadIdx.x;   // word index 0..131071
  int row = idx >> 6, wi = idx & 63;
  const int* p = mask + (long)row * 2048 + wi * 32;
  unsigned int bits = 0;
  #pragma unroll
  for (int j = 0; j < 32; j++) bits |= (p[j] != 0 ? 1u : 0u) << j;
  mbits[idx] = bits;
}

// ---------------- GEMM: C = A(MxK) * B(NxK)^T, bf16 in, m97-style ----------------
template <int MODE>
__global__ __launch_bounds__(256) void gemm_bt(const unsigned short* __restrict__ A,
                                               const unsigned short* __restrict__ B,
                                               void* __restrict__ Cv,
                                               int M, int N, int K) {
  __shared__ __align__(16) unsigned short As[128 * 64];
  __shared__ __align__(16) unsigned short Bs[128 * 64];
  const int tid = threadIdx.x;
  const int w = tid >> 6, l = tid & 63;
  const int wr = w >> 1, wc = w & 1;
  const long row0 = (long)blockIdx.y * 128;
  const long col0 = (long)blockIdx.x * 128;
  const int lr = l >> 3;          // 0..7
  const int lc = (l & 7) * 8;     // 0..56

  f32x4 acc[4][4];
  #pragma unroll
  for (int m = 0; m < 4; m++)
    #pragma unroll
    for (int n = 0; n < 4; n++) acc[m][n] = zero4();

  for (int k0 = 0; k0 < K; k0 += 64) {
    #pragma unroll
    for (int j = 0; j < 4; j++) {
      int slot = j * 4 + w;            // 0..15
      int row = slot * 8 + lr;         // 0..127
      gl_lds16(A + (row0 + row) * K + k0 + lc, &As[slot * 512]);
      gl_lds16(B + (col0 + row) * K + k0 + lc, &Bs[slot * 512]);
    }
    __syncthreads();
    #pragma unroll
    for (int kk = 0; kk < 2; kk++) {
      short8 a[4], b[4];
      #pragma unroll
      for (int m = 0; m < 4; m++)
        a[m] = *(const short8*)&As[(wr * 64 + m * 16 + (l & 15)) * 64 + kk * 32 + (l >> 4) * 8];
      #pragma unroll
      for (int n = 0; n < 4; n++)
        b[n] = *(const short8*)&Bs[(wc * 64 + n * 16 + (l & 15)) * 64 + kk * 32 + (l >> 4) * 8];
      #pragma unroll
      for (int m = 0; m < 4; m++)
        #pragma unroll
        for (int n = 0; n < 4; n++)
          acc[m][n] = MFMA16(a[m], b[n], acc[m][n]);
    }
    __syncthreads();
  }

  #pragma unroll
  for (int m = 0; m < 4; m++) {
    long rowb = row0 + wr * 64 + m * 16 + ((l >> 4) * 4);
    #pragma unroll
    for (int n = 0; n < 4; n++) {
      long colb = col0 + wc * 64 + n * 16 + (l & 15);
      if (MODE == 0) {
        unsigned short* C = (unsigned short*)Cv;
        #pragma unroll
        for (int r = 0; r < 4; r++) C[(rowb + r) * N + colb] = f2bf(acc[m][n][r]);
      } else if (MODE == 1) {
        unsigned short* C = (unsigned short*)Cv;
        long bb = rowb >> 11, s0 = rowb & 2047;
        u16x4 pk;
        pk.x = f2bf(acc[m][n][0]); pk.y = f2bf(acc[m][n][1]);
        pk.z = f2bf(acc[m][n][2]); pk.w = f2bf(acc[m][n][3]);
        *(u16x4*)&C[(bb * 1024 + colb) * 2048 + s0] = pk;
      } else {
        float* C = (float*)Cv;
        #pragma unroll
        for (int r = 0; r < 4; r++) C[(rowb + r) * N + colb] = acc[m][n][r];
      }
    }
  }
}

// ---------------- softmax (exp2-direct, masked) + pack + redistribute ----------------
__device__ __forceinline__ void softmax_pack(const f32x4* sf, unsigned long long mw,
                                             int g, int sA, int sB, int gh,
                                             float& l_run, short8& pa0o, short8& pa1o) {
  mw >>= (g * 4);
  unsigned int mlo = (unsigned int)mw, mhi = (unsigned int)(mw >> 32);
  float pv[16];
  float lsum = 0.f;
  #pragma unroll
  for (int kvq = 0; kvq < 4; kvq++) {
    unsigned int msel = (kvq < 2) ? mlo : mhi;
    #pragma unroll
    for (int r = 0; r < 4; r++) {
      float e = __builtin_amdgcn_exp2f(sf[kvq][r]);   // scale pre-folded into W_qk
      unsigned int bit = (msel >> (((kvq & 1) << 4) + r)) & 1u;
      float p = bit ? e : 0.0f;
      pv[kvq * 4 + r] = p;
      lsum += p;
    }
  }
  l_run += lsum;

  unsigned int pk0[2], pk1[2], pk2[2], pk3[2];
  pk0[0] = cvt_pk_bf16(pv[0],  pv[1]);  pk0[1] = cvt_pk_bf16(pv[2],  pv[3]);
  pk1[0] = cvt_pk_bf16(pv[4],  pv[5]);  pk1[1] = cvt_pk_bf16(pv[6],  pv[7]);
  pk2[0] = cvt_pk_bf16(pv[8],  pv[9]);  pk2[1] = cvt_pk_bf16(pv[10], pv[11]);
  pk3[0] = cvt_pk_bf16(pv[12], pv[13]); pk3[1] = cvt_pk_bf16(pv[14], pv[15]);

  u32x4 a0, a1;
  int t0, t1;
  t0 = __shfl((int)pk0[0], sA); t1 = __shfl((int)pk1[0], sA);
  a0.x = gh ? (unsigned)t1 : (unsigned)t0;
  t0 = __shfl((int)pk0[1], sA); t1 = __shfl((int)pk1[1], sA);
  a0.y = gh ? (unsigned)t1 : (unsigned)t0;
  t0 = __shfl((int)pk0[0], sB); t1 = __shfl((int)pk1[0], sB);
  a0.z = gh ? (unsigned)t1 : (unsigned)t0;
  t0 = __shfl((int)pk0[1], sB); t1 = __shfl((int)pk1[1], sB);
  a0.w = gh ? (unsigned)t1 : (unsigned)t0;
  t0 = __shfl((int)pk2[0], sA); t1 = __shfl((int)pk3[0], sA);
  a1.x = gh ? (unsigned)t1 : (unsigned)t0;
  t0 = __shfl((int)pk2[1], sA); t1 = __shfl((int)pk3[1], sA);
  a1.y = gh ? (unsigned)t1 : (unsigned)t0;
  t0 = __shfl((int)pk2[0], sB); t1 = __shfl((int)pk3[0], sB);
  a1.z = gh ? (unsigned)t1 : (unsigned)t0;
  t0 = __shfl((int)pk2[1], sB); t1 = __shfl((int)pk3[1], sB);
  a1.w = gh ? (unsigned)t1 : (unsigned)t0;
  pa0o = __builtin_bit_cast(short8, a0);
  pa1o = __builtin_bit_cast(short8, a1);
}

// ---------------- flash attention: 16 q/wave, V from global, K dbuf, 2-way KV split ----------------
// qk: (N*S) x 2048 bf16; vT: (N*H*64) x 2048 bf16; mbits: 2048 x 64 u32
// po0/po1: unnormalized O partials, bf16; pl0/pl1: l partials, f32 [(b*2048+q)*16 + h]
__global__ __launch_bounds__(256, 4) void attn(const unsigned short* __restrict__ qk,
                                               const unsigned short* __restrict__ vT,
                                               const unsigned int* __restrict__ mbits,
                                               unsigned short* __restrict__ po0,
                                               unsigned short* __restrict__ po1,
                                               float* __restrict__ pl0,
                                               float* __restrict__ pl1) {
  __shared__ __align__(16) unsigned short Ks[2][64 * 64];
  const int tid = threadIdx.x;
  const int w = tid >> 6, l = tid & 63;
  const int b = blockIdx.z, h = blockIdx.y;
  const int qt = blockIdx.x & 31, kvh = blockIdx.x >> 5;
  const int q0 = qt * 64;
  const int kvbase = kvh << 10;                  // 0 or 1024
  unsigned short* po = kvh ? po1 : po0;
  float* pl = kvh ? pl1 : pl0;
  const int c = l & 15, g = l >> 4;
  const int lr = l >> 3, pg = l & 7;

  // Q B-fragments for q-row = q0 + w*16 + c (pre-scaled by SC via W_qk)
  const int qrow = q0 + w * 16 + c;
  const unsigned short* qptr = qk + (long)(b * 2048 + qrow) * 2048 + h * 128;
  short8 bq0 = *(const short8*)&qptr[g * 8];
  short8 bq1 = *(const short8*)&qptr[32 + g * 8];

  const int sw0 = ((g)     ^ (c & 7)) * 8;
  const int sw1 = ((g + 4) ^ (c & 7)) * 8;
  const int sA = c + (((2 * g)     & 3) << 4);
  const int sB = c + (((2 * g + 1) & 3) << 4);
  const int gh = g >> 1;

  const unsigned int* mrowp = mbits + (long)qrow * 64;

  // K staging geometry (slot = w + j*4, row = slot*8 + lr, swizzled source col)
  const unsigned short* kbase = qk + (long)b * 2048 * 2048 + h * 128 + 64;
  const unsigned short* vbase = vT + (long)((b * 16 + h) * 64) * 2048;
  const int srow = w * 8 + lr;
  const int sgg = pg ^ (lr & 7);

  float l_run = 0.f;
  f32x4 o[4];
  #pragma unroll
  for (int d = 0; d < 4; d++) o[d] = zero4();

  // prologue: stage K tile 0 into buf 0
  #pragma unroll
  for (int j = 0; j < 2; j++)
    gl_lds16(kbase + (long)(kvbase + srow + j * 32) * 2048 + sgg * 8,
             &Ks[0][(w + j * 4) * 512]);
  __syncthreads();

  for (int it = 0; it < 16; it++) {
    const int kv0 = kvbase + it * 64;
    const int cur = it & 1;

    // issue next K tile's staging (overlaps with compute)
    if (it < 15) {
      #pragma unroll
      for (int j = 0; j < 2; j++)
        gl_lds16(kbase + (long)(kv0 + 64 + srow + j * 32) * 2048 + sgg * 8,
                 &Ks[cur ^ 1][(w + j * 4) * 512]);
    }

    // V fragments straight from global (L1/L2-resident), issued early;
    // QK^T + softmax below hides the latency
    short8 vf[8];
    #pragma unroll
    for (int dt = 0; dt < 4; dt++) {
      const unsigned short* vp = vbase + (long)(dt * 16 + c) * 2048 + kv0;
      vf[dt * 2]     = *(const short8*)&vp[g * 8];
      vf[dt * 2 + 1] = *(const short8*)&vp[32 + g * 8];
    }
    unsigned long long mw = *(const unsigned long long*)&mrowp[kv0 >> 5];

    // S^T = K Q^T : sf[kvq][r] = S[kv = kvq*16 + g*4 + r][q = c]
    f32x4 sf[4];
    #pragma unroll
    for (int kvq = 0; kvq < 4; kvq++) {
      int R = kvq * 16 + c;
      short8 ak0 = *(const short8*)&Ks[cur][R * 64 + sw0];
      short8 ak1 = *(const short8*)&Ks[cur][R * 64 + sw1];
      f32x4 z = zero4();
      z = MFMA16(ak0, bq0, z);
      z = MFMA16(ak1, bq1, z);
      sf[kvq] = z;
    }

    short8 pa0, pa1;
    softmax_pack(sf, mw, g, sA, sB, gh, l_run, pa0, pa1);

    // O += P V
    #pragma unroll
    for (int dt = 0; dt < 4; dt++) {
      o[dt] = MFMA16(pa0, vf[dt * 2],     o[dt]);
      o[dt] = MFMA16(pa1, vf[dt * 2 + 1], o[dt]);
    }

    __syncthreads();
  }

  // l partial reduction + stores
  l_run += __shfl_xor(l_run, 16);
  l_run += __shfl_xor(l_run, 32);
  if (g == 0) pl[((long)(b << 11) + qrow) * 16 + h] = l_run;
  #pragma unroll
  for (int dt = 0; dt < 4; dt++) {
    long rowb = (long)b * 2048 + q0 + w * 16 + g * 4;
    int col = h * 64 + dt * 16 + c;
    po[(rowb + 0) * 1024 + col] = f2bf(o[dt][0]);
    po[(rowb + 1) * 1024 + col] = f2bf(o[dt][1]);
    po[(rowb + 2) * 1024 + col] = f2bf(o[dt][2]);
    po[(rowb + 3) * 1024 + col] = f2bf(o[dt][3]);
  }
}

// ---------------- combine KV-split partials: vals = (o0+o1)/(l0+l1) ----------------
__global__ __launch_bounds__(256) void combine(const unsigned short* __restrict__ po0,
                                               const unsigned short* __restrict__ po1,
                                               const float* __restrict__ pl0,
                                               const float* __restrict__ pl1,
                                               unsigned short* __restrict__ vals) {
  int i = blockIdx.x * 256 + threadIdx.x;   // 0..524287, 8 cols each
  int q = i >> 7;                           // 0..4095 (b*2048+s)
  int col = (i & 127) * 8;                  // 0..1016, within one head block
  int h = col >> 6;
  float linv = 1.0f / (pl0[q * 16 + h] + pl1[q * 16 + h]);
  long off = (long)q * 1024 + col;
  short8 a = *(const short8*)&po0[off];
  short8 b = *(const short8*)&po1[off];
  short8 o;
  #pragma unroll
  for (int j = 0; j < 8; j++) {
    float fa = __builtin_bit_cast(float, ((unsigned int)(unsigned short)a[j]) << 16);
    float fb = __builtin_bit_cast(float, ((unsigned int)(unsigned short)b[j]) << 16);
    o[j] = (short)f2bf((fa + fb) * linv);
  }
  *(short8*)&vals[off] = o;
}

extern "C" void kernel_launch(void* const* d_in, const int* in_sizes, int n_in,
                              void* d_out, int out_size, void* d_ws, size_t ws_size,
                              hipStream_t stream) {
  const float* xe  = (const float*)d_in[0];
  const float* xd  = (const float*)d_in[1];
  const int*   msk = (const int*)d_in[2];
  const float* wqk = (const float*)d_in[3];
  const float* wv  = (const float*)d_in[4];
  const float* wo  = (const float*)d_in[5];
  float* out = (float*)d_out;
  unsigned short* ws = (unsigned short*)d_ws;

  // workspace layout (ushort elements):
  // [0, 4194304)            po0      | [4194304, 8388608)   po1
  // [8388608, 8519680)      pl0 f32  | [8519680, 8650752)   pl1 f32
  // [8650752, 12845056)     xe_bf    | [12845056, 17039360) xd_bf
  // [17039360, 19136512)    wqk_bf   | [19136512, 20185088) wv_bf
  // [20185088, 21233664)    wo_bf    | [21233664, 29622272) qkb (4096x2048)
  // [29622272, 33816576)    vTb      | [33816576, 38010880) valb (4096x1024)
  // [38010880, 38273024)    mbits u32
  unsigned short* po0    = ws;
  unsigned short* po1    = ws + 4194304;
  float*          pl0    = (float*)(ws + 8388608);
  float*          pl1    = (float*)(ws + 8519680);
  unsigned short* xe_bf  = ws + 8650752;
  unsigned short* xd_bf  = ws + 12845056;
  unsigned short* wqk_bf = ws + 17039360;
  unsigned short* wv_bf  = ws + 19136512;
  unsigned short* wo_bf  = ws + 20185088;
  unsigned short* qkb    = ws + 21233664;
  unsigned short* vTb    = ws + 29622272;
  unsigned short* valb   = ws + 33816576;
  unsigned int*   mbits  = (unsigned int*)(ws + 38010880);

  cvt_all<<<12288, 256, 0, stream>>>(xe, xd, wqk, wv, wo, ws);
  mask_pack<<<512, 256, 0, stream>>>(msk, mbits);
  gemm_bt<0><<<dim3(16, 32), 256, 0, stream>>>(xe_bf, wqk_bf, qkb, 4096, 2048, 1024);
  gemm_bt<1><<<dim3(8, 32), 256, 0, stream>>>(xd_bf, wv_bf, vTb, 4096, 1024, 1024);
  attn<<<dim3(64, 16, 2), 256, 0, stream>>>(qkb, vTb, mbits, po0, po1, pl0, pl1);
  combine<<<2048, 256, 0, stream>>>(po0, po1, pl0, pl1, valb);
  gemm_bt<2><<<dim3(8, 32), 256, 0, stream>>>(valb, wo_bf, out, 4096, 1024, 1024);
}

// Round 7
// 167.552 us; speedup vs baseline: 1.4531x; 1.4531x over previous
//
#include <hip/hip_runtime.h>

typedef __attribute__((ext_vector_type(8))) short short8;
typedef __attribute__((ext_vector_type(4))) float f32x4;
typedef __attribute__((ext_vector_type(4))) unsigned short u16x4;
typedef __attribute__((ext_vector_type(4))) unsigned int u32x4;

#define MFMA16(A,B,C) __builtin_amdgcn_mfma_f32_16x16x32_bf16(A,B,C,0,0,0)

__device__ __forceinline__ unsigned short f2bf(float f) {
  unsigned int u = __builtin_bit_cast(unsigned int, f);
  unsigned int r = (u + 0x7fffu + ((u >> 16) & 1u)) >> 16;
  return (unsigned short)r;
}

__device__ __forceinline__ unsigned int cvt_pk_bf16(float lo, float hi) {
  unsigned int r;
  asm("v_cvt_pk_bf16_f32 %0, %1, %2" : "=v"(r) : "v"(lo), "v"(hi));
  return r;
}

__device__ __forceinline__ f32x4 zero4() {
  f32x4 z; z.x = 0.f; z.y = 0.f; z.z = 0.f; z.w = 0.f; return z;
}

__device__ __forceinline__ void gl_lds16(const void* g, void* l) {
  __builtin_amdgcn_global_load_lds((const __attribute__((address_space(1))) void*)g,
                                   (__attribute__((address_space(3))) void*)l, 16, 0, 0);
}

// ---------------- convert all five f32 arrays to bf16 in one pass ----------------
// W_qk q-projection rows pre-scaled by (1/sqrt(hd))*log2(e) -> attn uses exp2 directly.
__global__ __launch_bounds__(256) void cvt_all(const float* __restrict__ xe,
                                               const float* __restrict__ xd,
                                               const float* __restrict__ wqk,
                                               const float* __restrict__ wv,
                                               const float* __restrict__ wo,
                                               unsigned short* __restrict__ ws) {
  long i = (long)blockIdx.x * 256 + threadIdx.x;  // float4 index
  const float* src; unsigned short* dst; long o; bool scl = false;
  if (i < 1048576)      { src = xe;  dst = ws + 8650752;  o = i; }            // xe_bf
  else if (i < 2097152) { src = xd;  dst = ws + 12845056; o = i - 1048576; }  // xd_bf
  else if (i < 2621440) { src = wqk; dst = ws + 17039360; o = i - 2097152;    // wqk_bf
                          scl = (((o >> 8) & 127) < 64); }                    // q rows
  else if (i < 2883584) { src = wv;  dst = ws + 19136512; o = i - 2621440; }  // wv_bf
  else                  { src = wo;  dst = ws + 20185088; o = i - 2883584; }  // wo_bf
  float4 f = ((const float4*)src)[o];
  if (scl) {
    const float SCQ = 0.125f * 1.4426950408889634f;
    f.x *= SCQ; f.y *= SCQ; f.z *= SCQ; f.w *= SCQ;
  }
  u16x4 r; r.x = f2bf(f.x); r.y = f2bf(f.y); r.z = f2bf(f.z); r.w = f2bf(f.w);
  ((u16x4*)dst)[o] = r;
}

// ---------------- pack mask (2048x2048 int32) into bits ----------------
__global__ __launch_bounds__(256) void mask_pack(const int* __restrict__ mask,
                                                 unsigned int* __restrict__ mbits) {
  int idx = blockIdx.x * 256 + threadIdx.x;   // word index 0..131071
  int row = idx >> 6, wi = idx & 63;
  const int* p = mask + (long)row * 2048 + wi * 32;
  unsigned int bits = 0;
  #pragma unroll
  for (int j = 0; j < 32; j++) bits |= (p[j] != 0 ? 1u : 0u) << j;
  mbits[idx] = bits;
}

// ---------------- GEMM: C = A(MxK) * B(NxK)^T, bf16 in, m97-style ----------------
template <int MODE>
__global__ __launch_bounds__(256) void gemm_bt(const unsigned short* __restrict__ A,
                                               const unsigned short* __restrict__ B,
                                               void* __restrict__ Cv,
                                               int M, int N, int K) {
  __shared__ __align__(16) unsigned short As[128 * 64];
  __shared__ __align__(16) unsigned short Bs[128 * 64];
  const int tid = threadIdx.x;
  const int w = tid >> 6, l = tid & 63;
  const int wr = w >> 1, wc = w & 1;
  const long row0 = (long)blockIdx.y * 128;
  const long col0 = (long)blockIdx.x * 128;
  const int lr = l >> 3;          // 0..7
  const int lc = (l & 7) * 8;     // 0..56

  f32x4 acc[4][4];
  #pragma unroll
  for (int m = 0; m < 4; m++)
    #pragma unroll
    for (int n = 0; n < 4; n++) acc[m][n] = zero4();

  for (int k0 = 0; k0 < K; k0 += 64) {
    #pragma unroll
    for (int j = 0; j < 4; j++) {
      int slot = j * 4 + w;            // 0..15
      int row = slot * 8 + lr;         // 0..127
      gl_lds16(A + (row0 + row) * K + k0 + lc, &As[slot * 512]);
      gl_lds16(B + (col0 + row) * K + k0 + lc, &Bs[slot * 512]);
    }
    __syncthreads();
    #pragma unroll
    for (int kk = 0; kk < 2; kk++) {
      short8 a[4], b[4];
      #pragma unroll
      for (int m = 0; m < 4; m++)
        a[m] = *(const short8*)&As[(wr * 64 + m * 16 + (l & 15)) * 64 + kk * 32 + (l >> 4) * 8];
      #pragma unroll
      for (int n = 0; n < 4; n++)
        b[n] = *(const short8*)&Bs[(wc * 64 + n * 16 + (l & 15)) * 64 + kk * 32 + (l >> 4) * 8];
      #pragma unroll
      for (int m = 0; m < 4; m++)
        #pragma unroll
        for (int n = 0; n < 4; n++)
          acc[m][n] = MFMA16(a[m], b[n], acc[m][n]);
    }
    __syncthreads();
  }

  #pragma unroll
  for (int m = 0; m < 4; m++) {
    long rowb = row0 + wr * 64 + m * 16 + ((l >> 4) * 4);
    #pragma unroll
    for (int n = 0; n < 4; n++) {
      long colb = col0 + wc * 64 + n * 16 + (l & 15);
      if (MODE == 0) {
        unsigned short* C = (unsigned short*)Cv;
        #pragma unroll
        for (int r = 0; r < 4; r++) C[(rowb + r) * N + colb] = f2bf(acc[m][n][r]);
      } else if (MODE == 1) {
        unsigned short* C = (unsigned short*)Cv;
        long bb = rowb >> 11, s0 = rowb & 2047;
        u16x4 pk;
        pk.x = f2bf(acc[m][n][0]); pk.y = f2bf(acc[m][n][1]);
        pk.z = f2bf(acc[m][n][2]); pk.w = f2bf(acc[m][n][3]);
        *(u16x4*)&C[(bb * 1024 + colb) * 2048 + s0] = pk;
      } else {
        float* C = (float*)Cv;
        #pragma unroll
        for (int r = 0; r < 4; r++) C[(rowb + r) * N + colb] = acc[m][n][r];
      }
    }
  }
}

// ---------------- softmax (exp2-direct, masked) + pack + redistribute ----------------
__device__ __forceinline__ void softmax_pack(const f32x4* sf, unsigned long long mw,
                                             int g, int sA, int sB, int gh,
                                             float& l_run, short8& pa0o, short8& pa1o) {
  mw >>= (g * 4);
  unsigned int mlo = (unsigned int)mw, mhi = (unsigned int)(mw >> 32);
  float pv[16];
  float lsum = 0.f;
  #pragma unroll
  for (int kvq = 0; kvq < 4; kvq++) {
    unsigned int msel = (kvq < 2) ? mlo : mhi;
    #pragma unroll
    for (int r = 0; r < 4; r++) {
      float e = __builtin_amdgcn_exp2f(sf[kvq][r]);   // scale pre-folded into W_qk
      unsigned int bit = (msel >> (((kvq & 1) << 4) + r)) & 1u;
      float p = bit ? e : 0.0f;
      pv[kvq * 4 + r] = p;
      lsum += p;
    }
  }
  l_run += lsum;

  unsigned int pk0[2], pk1[2], pk2[2], pk3[2];
  pk0[0] = cvt_pk_bf16(pv[0],  pv[1]);  pk0[1] = cvt_pk_bf16(pv[2],  pv[3]);
  pk1[0] = cvt_pk_bf16(pv[4],  pv[5]);  pk1[1] = cvt_pk_bf16(pv[6],  pv[7]);
  pk2[0] = cvt_pk_bf16(pv[8],  pv[9]);  pk2[1] = cvt_pk_bf16(pv[10], pv[11]);
  pk3[0] = cvt_pk_bf16(pv[12], pv[13]); pk3[1] = cvt_pk_bf16(pv[14], pv[15]);

  u32x4 a0, a1;
  int t0, t1;
  t0 = __shfl((int)pk0[0], sA); t1 = __shfl((int)pk1[0], sA);
  a0.x = gh ? (unsigned)t1 : (unsigned)t0;
  t0 = __shfl((int)pk0[1], sA); t1 = __shfl((int)pk1[1], sA);
  a0.y = gh ? (unsigned)t1 : (unsigned)t0;
  t0 = __shfl((int)pk0[0], sB); t1 = __shfl((int)pk1[0], sB);
  a0.z = gh ? (unsigned)t1 : (unsigned)t0;
  t0 = __shfl((int)pk0[1], sB); t1 = __shfl((int)pk1[1], sB);
  a0.w = gh ? (unsigned)t1 : (unsigned)t0;
  t0 = __shfl((int)pk2[0], sA); t1 = __shfl((int)pk3[0], sA);
  a1.x = gh ? (unsigned)t1 : (unsigned)t0;
  t0 = __shfl((int)pk2[1], sA); t1 = __shfl((int)pk3[1], sA);
  a1.y = gh ? (unsigned)t1 : (unsigned)t0;
  t0 = __shfl((int)pk2[0], sB); t1 = __shfl((int)pk3[0], sB);
  a1.z = gh ? (unsigned)t1 : (unsigned)t0;
  t0 = __shfl((int)pk2[1], sB); t1 = __shfl((int)pk3[1], sB);
  a1.w = gh ? (unsigned)t1 : (unsigned)t0;
  pa0o = __builtin_bit_cast(short8, a0);
  pa1o = __builtin_bit_cast(short8, a1);
}

// ---------------- flash attention: 32 q/wave, K+V LDS dbuf, 2-way KV split ----------------
// qk: (N*S) x 2048 bf16; vT: (N*H*64) x 2048 bf16; mbits: 2048 x 64 u32
// po0/po1: unnormalized O partials bf16; pl0/pl1: l partials f32 [(b*2048+q)*16 + h]
__global__ __launch_bounds__(256, 4) void attn(const unsigned short* __restrict__ qk,
                                               const unsigned short* __restrict__ vT,
                                               const unsigned int* __restrict__ mbits,
                                               unsigned short* __restrict__ po0,
                                               unsigned short* __restrict__ po1,
                                               float* __restrict__ pl0,
                                               float* __restrict__ pl1) {
  __shared__ __align__(16) unsigned short Ks[2][64 * 64];
  __shared__ __align__(16) unsigned short Vs[2][64 * 64];
  const int tid = threadIdx.x;
  const int w = tid >> 6, l = tid & 63;
  const int b = blockIdx.z, h = blockIdx.y;
  const int qt = blockIdx.x & 15, kvh = blockIdx.x >> 4;
  const int q0 = qt * 128;
  const int kvbase = kvh << 10;                  // 0 or 1024
  unsigned short* po = kvh ? po1 : po0;
  float* pl = kvh ? pl1 : pl0;
  const int c = l & 15, g = l >> 4;
  const int lr = l >> 3, pg = l & 7;

  // two q-rows per lane: qa (set A) and qb = qa+16 (set B); Q pre-scaled via W_qk
  const int qa = q0 + w * 32 + c;
  const int qb = qa + 16;
  const unsigned short* qptrA = qk + (long)(b * 2048 + qa) * 2048 + h * 128;
  const unsigned short* qptrB = qk + (long)(b * 2048 + qb) * 2048 + h * 128;
  short8 bqA0 = *(const short8*)&qptrA[g * 8];
  short8 bqA1 = *(const short8*)&qptrA[32 + g * 8];
  short8 bqB0 = *(const short8*)&qptrB[g * 8];
  short8 bqB1 = *(const short8*)&qptrB[32 + g * 8];

  const int sw0 = ((g)     ^ (c & 7)) * 8;
  const int sw1 = ((g + 4) ^ (c & 7)) * 8;
  const int sA = c + (((2 * g)     & 3) << 4);
  const int sB = c + (((2 * g + 1) & 3) << 4);
  const int gh = g >> 1;

  const unsigned int* mrowA = mbits + (long)qa * 64;
  const unsigned int* mrowB = mbits + (long)qb * 64;

  // staging geometry (slot = w + j*4, row = slot*8 + lr, XOR-swizzled source col)
  const unsigned short* kbase = qk + (long)b * 2048 * 2048 + h * 128 + 64;
  const unsigned short* vbase = vT + (long)((b * 16 + h) * 64) * 2048;
  const int srow = w * 8 + lr;
  const int sgg = pg ^ (lr & 7);

  float lA = 0.f, lB = 0.f;
  f32x4 oA[4], oB[4];
  #pragma unroll
  for (int d = 0; d < 4; d++) { oA[d] = zero4(); oB[d] = zero4(); }

  // prologue: stage K,V tile 0 into buf 0
  #pragma unroll
  for (int j = 0; j < 2; j++) {
    int row = srow + j * 32;
    gl_lds16(kbase + (long)(kvbase + row) * 2048 + sgg * 8, &Ks[0][(w + j * 4) * 512]);
    gl_lds16(vbase + (long)row * 2048 + kvbase + sgg * 8,   &Vs[0][(w + j * 4) * 512]);
  }
  __syncthreads();

  for (int it = 0; it < 16; it++) {
    const int kv0 = kvbase + it * 64;
    const int cur = it & 1;

    // issue next tile's staging (async, drained by the end-of-iter barrier)
    if (it < 15) {
      #pragma unroll
      for (int j = 0; j < 2; j++) {
        int row = srow + j * 32;
        gl_lds16(kbase + (long)(kv0 + 64 + row) * 2048 + sgg * 8,
                 &Ks[cur ^ 1][(w + j * 4) * 512]);
        gl_lds16(vbase + (long)row * 2048 + kv0 + 64 + sgg * 8,
                 &Vs[cur ^ 1][(w + j * 4) * 512]);
      }
    }

    unsigned long long mwA = *(const unsigned long long*)&mrowA[kv0 >> 5];
    unsigned long long mwB = *(const unsigned long long*)&mrowB[kv0 >> 5];

    // S^T = K Q^T for both q-sets; K fragments read once from LDS, reused
    f32x4 sfA[4], sfB[4];
    #pragma unroll
    for (int kvq = 0; kvq < 4; kvq++) {
      int R = kvq * 16 + c;
      short8 ak0 = *(const short8*)&Ks[cur][R * 64 + sw0];
      short8 ak1 = *(const short8*)&Ks[cur][R * 64 + sw1];
      f32x4 zA = zero4();
      zA = MFMA16(ak0, bqA0, zA);
      zA = MFMA16(ak1, bqA1, zA);
      sfA[kvq] = zA;
      f32x4 zB = zero4();
      zB = MFMA16(ak0, bqB0, zB);
      zB = MFMA16(ak1, bqB1, zB);
      sfB[kvq] = zB;
    }

    short8 paA0, paA1, paB0, paB1;
    softmax_pack(sfA, mwA, g, sA, sB, gh, lA, paA0, paA1);
    softmax_pack(sfB, mwB, g, sA, sB, gh, lB, paB0, paB1);

    // O += P V ; V fragments read once from LDS, reused across q-sets
    #pragma unroll
    for (int dt = 0; dt < 4; dt++) {
      int d = dt * 16 + c;
      short8 bv0 = *(const short8*)&Vs[cur][d * 64 + sw0];
      short8 bv1 = *(const short8*)&Vs[cur][d * 64 + sw1];
      oA[dt] = MFMA16(paA0, bv0, oA[dt]);
      oA[dt] = MFMA16(paA1, bv1, oA[dt]);
      oB[dt] = MFMA16(paB0, bv0, oB[dt]);
      oB[dt] = MFMA16(paB1, bv1, oB[dt]);
    }

    __syncthreads();
  }

  // l partial reductions + stores for both q-sets
  lA += __shfl_xor(lA, 16); lA += __shfl_xor(lA, 32);
  lB += __shfl_xor(lB, 16); lB += __shfl_xor(lB, 32);
  if (g == 0) {
    pl[((long)(b << 11) + qa) * 16 + h] = lA;
    pl[((long)(b << 11) + qb) * 16 + h] = lB;
  }
  #pragma unroll
  for (int dt = 0; dt < 4; dt++) {
    long rowA = (long)b * 2048 + q0 + w * 32 + g * 4;
    long rowB = rowA + 16;
    int col = h * 64 + dt * 16 + c;
    po[(rowA + 0) * 1024 + col] = f2bf(oA[dt][0]);
    po[(rowA + 1) * 1024 + col] = f2bf(oA[dt][1]);
    po[(rowA + 2) * 1024 + col] = f2bf(oA[dt][2]);
    po[(rowA + 3) * 1024 + col] = f2bf(oA[dt][3]);
    po[(rowB + 0) * 1024 + col] = f2bf(oB[dt][0]);
    po[(rowB + 1) * 1024 + col] = f2bf(oB[dt][1]);
    po[(rowB + 2) * 1024 + col] = f2bf(oB[dt][2]);
    po[(rowB + 3) * 1024 + col] = f2bf(oB[dt][3]);
  }
}

// ---------------- combine KV-split partials: vals = (o0+o1)/(l0+l1) ----------------
__global__ __launch_bounds__(256) void combine(const unsigned short* __restrict__ po0,
                                               const unsigned short* __restrict__ po1,
                                               const float* __restrict__ pl0,
                                               const float* __restrict__ pl1,
                                               unsigned short* __restrict__ vals) {
  int i = blockIdx.x * 256 + threadIdx.x;   // 0..524287, 8 cols each
  int q = i >> 7;                           // 0..4095 (b*2048+s)
  int col = (i & 127) * 8;                  // 0..1016, within one head block
  int h = col >> 6;
  float linv = 1.0f / (pl0[q * 16 + h] + pl1[q * 16 + h]);
  long off = (long)q * 1024 + col;
  short8 a = *(const short8*)&po0[off];
  short8 b = *(const short8*)&po1[off];
  short8 o;
  #pragma unroll
  for (int j = 0; j < 8; j++) {
    float fa = __builtin_bit_cast(float, ((unsigned int)(unsigned short)a[j]) << 16);
    float fb = __builtin_bit_cast(float, ((unsigned int)(unsigned short)b[j]) << 16);
    o[j] = (short)f2bf((fa + fb) * linv);
  }
  *(short8*)&vals[off] = o;
}

extern "C" void kernel_launch(void* const* d_in, const int* in_sizes, int n_in,
                              void* d_out, int out_size, void* d_ws, size_t ws_size,
                              hipStream_t stream) {
  const float* xe  = (const float*)d_in[0];
  const float* xd  = (const float*)d_in[1];
  const int*   msk = (const int*)d_in[2];
  const float* wqk = (const float*)d_in[3];
  const float* wv  = (const float*)d_in[4];
  const float* wo  = (const float*)d_in[5];
  float* out = (float*)d_out;
  unsigned short* ws = (unsigned short*)d_ws;

  // workspace layout (ushort elements):
  // [0, 4194304)            po0      | [4194304, 8388608)   po1
  // [8388608, 8519680)      pl0 f32  | [8519680, 8650752)   pl1 f32
  // [8650752, 12845056)     xe_bf    | [12845056, 17039360) xd_bf
  // [17039360, 19136512)    wqk_bf   | [19136512, 20185088) wv_bf
  // [20185088, 21233664)    wo_bf    | [21233664, 29622272) qkb (4096x2048)
  // [29622272, 33816576)    vTb      | [33816576, 38010880) valb (4096x1024)
  // [38010880, 38273024)    mbits u32
  unsigned short* po0    = ws;
  unsigned short* po1    = ws + 4194304;
  float*          pl0    = (float*)(ws + 8388608);
  float*          pl1    = (float*)(ws + 8519680);
  unsigned short* xe_bf  = ws + 8650752;
  unsigned short* xd_bf  = ws + 12845056;
  unsigned short* wqk_bf = ws + 17039360;
  unsigned short* wv_bf  = ws + 19136512;
  unsigned short* wo_bf  = ws + 20185088;
  unsigned short* qkb    = ws + 21233664;
  unsigned short* vTb    = ws + 29622272;
  unsigned short* valb   = ws + 33816576;
  unsigned int*   mbits  = (unsigned int*)(ws + 38010880);

  cvt_all<<<12288, 256, 0, stream>>>(xe, xd, wqk, wv, wo, ws);
  mask_pack<<<512, 256, 0, stream>>>(msk, mbits);
  gemm_bt<0><<<dim3(16, 32), 256, 0, stream>>>(xe_bf, wqk_bf, qkb, 4096, 2048, 1024);
  gemm_bt<1><<<dim3(8, 32), 256, 0, stream>>>(xd_bf, wv_bf, vTb, 4096, 1024, 1024);
  attn<<<dim3(32, 16, 2), 256, 0, stream>>>(qkb, vTb, mbits, po0, po1, pl0, pl1);
  combine<<<2048, 256, 0, stream>>>(po0, po1, pl0, pl1, valb);
  gemm_bt<2><<<dim3(8, 32), 256, 0, stream>>>(valb, wo_bf, out, 4096, 1024, 1024);
}